// Round 22
// baseline (1356.083 us; speedup 1.0000x reference)
//
#include <hip/hip_runtime.h>
#include <hip/hip_bf16.h>

#define L_ 8
#define H_ 16
#define C_ 1024
#define B_ 2
#define T_ 1024
#define M_ (B_*T_)   // 2048 rows
#define DH 64
#define FF (4*C_)    // 4096

typedef __hip_bfloat16 bf16;
typedef __attribute__((ext_vector_type(8))) short s16x8;
typedef __attribute__((ext_vector_type(4))) float f32x4;
typedef __attribute__((ext_vector_type(16))) float f32x16;

enum { EPI_QKV = 0, EPI_RESID = 1, EPI_GELU = 2, EPI_PARTIAL = 3 };

#define WSLAB 12582912  // bf16 elems per layer in wt slab: 3M qkv | 1M proj | 4M up | 4M down

__device__ __forceinline__ void gload16(const void* g, void* l) {
    __builtin_amdgcn_global_load_lds(
        (const __attribute__((address_space(1))) unsigned int*)g,
        (__attribute__((address_space(3))) unsigned int*)l, 16, 0, 0);
}

__device__ __forceinline__ unsigned short bfb(float x) {
    return __builtin_bit_cast(unsigned short, __float2bfloat16(x));
}

__device__ __forceinline__ unsigned packbf(float lo, float hi) {
    return (unsigned)bfb(lo) | ((unsigned)bfb(hi) << 16);
}

// ---------------- LayerNorm (one block per row, C=1024, 256 threads) ----------------
__device__ __forceinline__ void stv(float* p, float v) { *p = v; }
__device__ __forceinline__ void stv(bf16* p, float v) { *p = __float2bfloat16(v); }

template<typename OutT>
__global__ __launch_bounds__(256) void ln_kernel(const float* __restrict__ x,
                                                 const float* __restrict__ w,
                                                 const float* __restrict__ b,
                                                 OutT* __restrict__ out) {
    int row = blockIdx.x;
    const float* xr = x + (size_t)row * C_;
    int t = threadIdx.x;
    float4 v = *(const float4*)(xr + t * 4);

    float s = v.x + v.y + v.z + v.w;
#pragma unroll
    for (int o = 32; o >= 1; o >>= 1) s += __shfl_xor(s, o);
    __shared__ float red[4];
    int wid = t >> 6, lane = t & 63;
    if (lane == 0) red[wid] = s;
    __syncthreads();
    float mean = (red[0] + red[1] + red[2] + red[3]) * (1.0f / C_);
    __syncthreads();

    float dx = v.x - mean, dy = v.y - mean, dz = v.z - mean, dw = v.w - mean;
    float ss = dx * dx + dy * dy + dz * dz + dw * dw;
#pragma unroll
    for (int o = 32; o >= 1; o >>= 1) ss += __shfl_xor(ss, o);
    if (lane == 0) red[wid] = ss;
    __syncthreads();
    float var = (red[0] + red[1] + red[2] + red[3]) * (1.0f / C_);
    float rs = rsqrtf(var + 1e-5f);

    float4 wv = *(const float4*)(w + t * 4);
    float4 bv = *(const float4*)(b + t * 4);
    OutT* orow = out + (size_t)row * C_;
    stv(orow + t * 4 + 0, dx * rs * wv.x + bv.x);
    stv(orow + t * 4 + 1, dy * rs * wv.y + bv.y);
    stv(orow + t * 4 + 2, dz * rs * wv.z + bv.z);
    stv(orow + t * 4 + 3, dw * rs * wv.w + bv.w);
}

// ---- weight transpose v4: fp32 [Kd][Nd] -> bf16 [Nd][Kd]; 64x64 tiles ----
// NOTE: per-layer dispatch (not PRE) is deliberate — keeps each 24MB slab L2/L3-hot
// for the GEMMs that consume it immediately (PRE measured +140us, round 15).
__global__ __launch_bounds__(256) void transpose_all_k(const float* __restrict__ Wq,
                                                       const float* __restrict__ Wk,
                                                       const float* __restrict__ Wv,
                                                       const float* __restrict__ Wp,
                                                       const float* __restrict__ W1,
                                                       const float* __restrict__ W2,
                                                       bf16* __restrict__ wt, int l0) {
    int layer = l0 + blockIdx.z;
    bf16* slab = wt + (size_t)blockIdx.z * WSLAB;
    int idx = blockIdx.x;  // 3072 tiles of 64x64 per layer
    const float* W; bf16* dst; int Kd, Nd;
    if (idx < 768) {
        int z = idx >> 8;
        W = ((z == 0) ? Wq : (z == 1) ? Wk : Wv) + (size_t)layer * C_ * C_;
        dst = slab + (size_t)z * 1048576; Kd = C_; Nd = C_; idx &= 255;
    } else if (idx < 1024) {
        W = Wp + (size_t)layer * C_ * C_;
        dst = slab + (size_t)3 * 1048576; Kd = C_; Nd = C_; idx -= 768;
    } else if (idx < 2048) {
        W = W1 + (size_t)layer * C_ * FF;
        dst = slab + (size_t)4 * 1048576; Kd = C_; Nd = FF; idx -= 1024;
    } else {
        W = W2 + (size_t)layer * FF * C_;
        dst = slab + (size_t)8 * 1048576; Kd = FF; Nd = C_; idx -= 2048;
    }
    int ntx = Nd >> 6;
    int gx = (idx & (ntx - 1)) << 6, gy = (idx / ntx) << 6;  // gx over Nd, gy over Kd

    __shared__ __align__(8) unsigned short tile[64][66];  // 132B row stride
    int tid = threadIdx.x, wid = tid >> 6, lane = tid & 63;
#pragma unroll
    for (int i = 0; i < 4; ++i) {
        int s = i * 256 + tid, r = s >> 4, c4 = (s & 15) * 4;
        float4 v = *(const float4*)(W + (size_t)(gy + r) * Nd + gx + c4);
        union { unsigned short us[4]; unsigned long long u64; } pk_;
        pk_.us[0] = bfb(v.x); pk_.us[1] = bfb(v.y); pk_.us[2] = bfb(v.z); pk_.us[3] = bfb(v.w);
        *(unsigned long long*)&tile[r][c4] = pk_.u64;
    }
    __syncthreads();
    int k0 = (lane & 7) * 8;
#pragma unroll
    for (int i = 0; i < 2; ++i) {
        int n = wid * 16 + (lane >> 3) + 8 * i;
        union { unsigned short us[8]; s16x8 v; } w;
#pragma unroll
        for (int j = 0; j < 8; ++j) w.us[j] = tile[k0 + j][n];
        *(s16x8*)&dst[(size_t)(gx + n) * Kd + gy + k0] = w.v;
    }
}

// ------- MFMA GEMM tile: 32x32x16 bf16, BK=64, dbuf LDS (stage t+1 || compute t), XOR swizzle -------
// 256 threads = 2x2 waves; wave tile (BM/2)x(BN/2).
template<int BM, int BN, int EPI>
__device__ __forceinline__ void gemm_tile(const bf16* __restrict__ A_, int lda,
                                          const bf16* __restrict__ Bt_, int ldb,
                                          const float* __restrict__ bias,
                                          const float* __restrict__ bias2,
                                          const float* __restrict__ bias3,
                                          const float* __restrict__ rsrc,
                                          void* __restrict__ C0, void* __restrict__ C1,
                                          void* __restrict__ C2, int ldc,
                                          int K, int bm0, int bn0) {
    constexpr int WM = BM / 2, WN = BN / 2, MR = WM / 32, NR = WN / 32;
    __shared__ __align__(16) short As[2][BM * 64];
    __shared__ __align__(16) short Bs[2][BN * 64];
    const short* Ap = (const short*)A_;
    const short* Bp = (const short*)Bt_;

    int tid = threadIdx.x;
    int wid = tid >> 6, lane = tid & 63;
    int la = lane & 31, lk = lane >> 5;     // frag row, k-half
    int wr = wid >> 1, wc = wid & 1;
    int sa = la & 7;                         // read-side swizzle key (row&7)

    auto stage = [&](int bf, int k0) {
        // SOURCE-side swizzle, linear LDS dest (rule #21)
#pragma unroll
        for (int i = 0; i < BM / 32; ++i) {
            int slot = i * 256 + tid;
            int row = slot >> 3, cs = (slot & 7) ^ (row & 7);
            gload16(Ap + (size_t)(bm0 + row) * lda + (k0 + cs * 8),
                    &As[bf][(i * 256 + wid * 64) * 8]);
        }
#pragma unroll
        for (int i = 0; i < BN / 32; ++i) {
            int slot = i * 256 + tid;
            int row = slot >> 3, cs = (slot & 7) ^ (row & 7);
            gload16(Bp + (size_t)(bn0 + row) * ldb + (k0 + cs * 8),
                    &Bs[bf][(i * 256 + wid * 64) * 8]);
        }
    };

    f32x16 acc[MR][NR];
#pragma unroll
    for (int m = 0; m < MR; ++m)
#pragma unroll
        for (int n = 0; n < NR; ++n)
#pragma unroll
            for (int i = 0; i < 16; ++i) acc[m][n][i] = 0.f;

    stage(0, 0);
    asm volatile("s_waitcnt vmcnt(0)" ::: "memory");
    __syncthreads();
    int cur = 0;

    for (int k0 = 0; k0 < K; k0 += 64) {
        if (k0 + 64 < K) stage(cur ^ 1, k0 + 64);  // prefetch next tile (overlaps compute)

        s16x8 af[MR][4], bfv[NR][4];
#pragma unroll
        for (int m = 0; m < MR; ++m)
#pragma unroll
            for (int kk = 0; kk < 4; ++kk)
                af[m][kk] = *(const s16x8*)&As[cur][(wr * WM + m * 32 + la) * 64 +
                                                   (((kk * 2 + lk) ^ sa) * 8)];
#pragma unroll
        for (int n = 0; n < NR; ++n)
#pragma unroll
            for (int kk = 0; kk < 4; ++kk)
                bfv[n][kk] = *(const s16x8*)&Bs[cur][(wc * WN + n * 32 + la) * 64 +
                                                    (((kk * 2 + lk) ^ sa) * 8)];
#pragma unroll
        for (int m = 0; m < MR; ++m)
#pragma unroll
            for (int n = 0; n < NR; ++n)
#pragma unroll
                for (int kk = 0; kk < 4; ++kk)
                    acc[m][n] = __builtin_amdgcn_mfma_f32_32x32x16_bf16(af[m][kk], bfv[n][kk],
                                                                        acc[m][n], 0, 0, 0);

        asm volatile("s_waitcnt vmcnt(0)" ::: "memory");  // stage(t+1) landed
        __syncthreads();
        cur ^= 1;
    }

    // epilogue: 32x32 C/D layout col=lane&31, row=(i&3)+8*(i>>2)+4*(lane>>5)  [verified m74/m101]
#pragma unroll
    for (int m = 0; m < MR; ++m)
#pragma unroll
        for (int n = 0; n < NR; ++n)
#pragma unroll
            for (int i = 0; i < 16; ++i) {
                int gm = bm0 + wr * WM + m * 32 + (i & 3) + 8 * (i >> 2) + 4 * lk;
                int gn = bn0 + wc * WN + n * 32 + la;
                float v = acc[m][n][i];
                if constexpr (EPI == EPI_QKV) {
                    if (gn < 1024) {
                        ((bf16*)C0)[(size_t)gm * C_ + gn] = __float2bfloat16(v + bias[gn]);
                    } else if (gn < 2048) {
                        ((bf16*)C1)[(size_t)gm * C_ + (gn - 1024)] =
                            __float2bfloat16(v + bias2[gn - 1024]);
                    } else {
                        int d = gn - 2048, bb = gm >> 10, tt = gm & 1023;
                        ((bf16*)C2)[((size_t)(bb * 1024 + d)) * T_ + tt] =
                            __float2bfloat16(v + bias3[d]);
                    }
                } else if constexpr (EPI == EPI_RESID) {
                    // read residual from rsrc (x for layer 0, h otherwise), write h
                    ((float*)C0)[(size_t)gm * ldc + gn] =
                        rsrc[(size_t)gm * ldc + gn] + v + bias[gn];
                } else if constexpr (EPI == EPI_GELU) {
                    float xg = v + bias[gn];
                    float g = 0.5f * xg * (1.0f + erff(xg * 0.70710678118654752f));
                    ((bf16*)C0)[(size_t)gm * ldc + gn] = __float2bfloat16(g);
                } else if constexpr (EPI == EPI_PARTIAL) {
                    ((float*)C0)[(size_t)gm * ldc + gn] = v;
                }
            }
}

template<int BM, int BN, int EPI>
__global__ __launch_bounds__(256) void gemm_k(const bf16* A, int lda, const bf16* Bt, int ldb,
                                              const float* bias, const float* rsrc,
                                              void* C0, int ldc, int K) {
    gemm_tile<BM, BN, EPI>(A, lda, Bt, ldb, bias, nullptr, nullptr, rsrc,
                           C0, nullptr, nullptr, ldc, K, blockIdx.y * BM, blockIdx.x * BN);
}

// QKV: 64x128 tile -> grid 24x32 = 768 blocks = 3/CU
__global__ __launch_bounds__(256) void gemm_qkv_k(const bf16* a, const bf16* wt,
                                                  const float* bq, const float* bk, const float* bv,
                                                  bf16* qb, bf16* kb, bf16* vT) {
    gemm_tile<64, 128, EPI_QKV>(a, C_, wt, C_, bq, bk, bv, nullptr, qb, kb, vT, 0, C_,
                                blockIdx.y * 64, blockIdx.x * 128);
}

// split-K over blockIdx.z; 64x128 tile -> 8x32x4 = 1024 blocks (3 resident/CU by LDS)
__global__ __launch_bounds__(256) void gemm_splitk_k(const bf16* A, int lda, const bf16* Bt, int ldb,
                                                     float* part, int Ksl) {
    int z = blockIdx.z;
    gemm_tile<64, 128, EPI_PARTIAL>(A + (size_t)z * Ksl, lda, Bt + (size_t)z * Ksl, ldb,
                                    nullptr, nullptr, nullptr, nullptr,
                                    part + (size_t)z * M_ * C_, nullptr, nullptr, C_, Ksl,
                                    blockIdx.y * 64, blockIdx.x * 128);
}

// ---- split-K combine (+bias +residual into h), optionally fused next-layer LN1 -> a ----
template<int NPART, bool LN>
__global__ __launch_bounds__(256) void combine_ln_k(float* __restrict__ h,
                                                    const float* __restrict__ part,
                                                    const float* __restrict__ bias,
                                                    const float* __restrict__ lw,
                                                    const float* __restrict__ lb,
                                                    bf16* __restrict__ aout) {
    int row = blockIdx.x, t = threadIdx.x;
    float4 hv = ((const float4*)(h + (size_t)row * C_))[t];
    float4 bb = ((const float4*)bias)[t];
    hv.x += bb.x; hv.y += bb.y; hv.z += bb.z; hv.w += bb.w;
#pragma unroll
    for (int z = 0; z < NPART; ++z) {
        float4 p = ((const float4*)(part + (size_t)z * M_ * C_ + (size_t)row * C_))[t];
        hv.x += p.x; hv.y += p.y; hv.z += p.z; hv.w += p.w;
    }
    ((float4*)(h + (size_t)row * C_))[t] = hv;

    if constexpr (LN) {
        float s = hv.x + hv.y + hv.z + hv.w;
#pragma unroll
        for (int o = 32; o >= 1; o >>= 1) s += __shfl_xor(s, o);
        __shared__ float red[4];
        int wid = t >> 6, lane = t & 63;
        if (lane == 0) red[wid] = s;
        __syncthreads();
        float mean = (red[0] + red[1] + red[2] + red[3]) * (1.0f / C_);
        __syncthreads();
        float dx = hv.x - mean, dy = hv.y - mean, dz = hv.z - mean, dw = hv.w - mean;
        float ss = dx * dx + dy * dy + dz * dz + dw * dw;
#pragma unroll
        for (int o = 32; o >= 1; o >>= 1) ss += __shfl_xor(ss, o);
        if (lane == 0) red[wid] = ss;
        __syncthreads();
        float var = (red[0] + red[1] + red[2] + red[3]) * (1.0f / C_);
        float rs = rsqrtf(var + 1e-5f);
        float4 wv = ((const float4*)lw)[t];
        float4 bv = ((const float4*)lb)[t];
        bf16* ar = aout + (size_t)row * C_;
        ar[t * 4 + 0] = __float2bfloat16(dx * rs * wv.x + bv.x);
        ar[t * 4 + 1] = __float2bfloat16(dy * rs * wv.y + bv.y);
        ar[t * 4 + 2] = __float2bfloat16(dz * rs * wv.z + bv.z);
        ar[t * 4 + 3] = __float2bfloat16(dw * rs * wv.w + bv.w);
    }
}

// ---------------- Flash attention: one block per (64-q tile, head pair) ----------------
// defer-max (T13). Work-balanced qt remap: co-resident blocks f and f+256 (same x,
// y vs y+16) get qt = x and 15-x, so each CU's pair sums to 17 tile-steps.
__global__ __launch_bounds__(256) void flash_k(const bf16* __restrict__ qb,
                                               const bf16* __restrict__ kb,
                                               const bf16* __restrict__ vT,
                                               bf16* __restrict__ yb) {
    int pair = blockIdx.y;
    int qt = (pair >= 16) ? (15 - blockIdx.x) : blockIdx.x;
    int bb = pair >> 4, hh = pair & 15;
    __shared__ __align__(16) short Ks[2][64 * 64];
    __shared__ __align__(16) short Vs[2][64 * 64];

    int tid = threadIdx.x, wid = tid >> 6, lane = tid & 63, lr = lane & 15, lg = lane >> 4;
    int qrow = qt * 64 + wid * 16 + lr;

    const short* qp = (const short*)qb + ((size_t)(bb * T_ + qrow)) * C_ + hh * 64;
    s16x8 qf[2];
    qf[0] = *(const s16x8*)(qp + lg * 8);
    qf[1] = *(const s16x8*)(qp + 32 + lg * 8);

    const short* kbase = (const short*)kb + ((size_t)bb * T_) * C_ + hh * 64;  // row kv, stride C_
    const short* vbase = (const short*)vT + ((size_t)pair * 64) * T_;          // row d, stride T_

    auto stage = [&](int bf, int t) {
        int kv0 = t * 64;
#pragma unroll
        for (int i = 0; i < 2; ++i) {
            int slot = i * 256 + tid;
            int row = slot >> 3, cs = (slot & 7) ^ (row & 7);
            gload16(kbase + (size_t)(kv0 + row) * C_ + cs * 8, &Ks[bf][(i * 256 + wid * 64) * 8]);
        }
#pragma unroll
        for (int i = 0; i < 2; ++i) {
            int slot = i * 256 + tid;
            int row = slot >> 3, cs = (slot & 7) ^ (row & 7);
            gload16(vbase + (size_t)row * T_ + kv0 + cs * 8, &Vs[bf][(i * 256 + wid * 64) * 8]);
        }
    };

    f32x4 oacc[4];
    const f32x4 z4 = {0.f, 0.f, 0.f, 0.f};
#pragma unroll
    for (int m = 0; m < 4; ++m) oacc[m] = z4;
    float mrun = -INFINITY, lrun = 0.f;

    int srcl[4];
#pragma unroll
    for (int r = 0; r < 4; ++r) srcl[r] = ((((lg << 3) + 2 * r) & 15) >> 2) * 16 + lr;
    bool hihalf = lg >= 2;
    int swz = lr & 7;

    stage(0, 0);
    asm volatile("s_waitcnt vmcnt(0)" ::: "memory");
    __syncthreads();
    int cur = 0;

    for (int t = 0; t <= qt; ++t) {
        int kv0 = t * 64;
        if (t < qt) stage(cur ^ 1, t + 1);  // prefetch next tile into the other buffer

        f32x4 sacc[4];
#pragma unroll
        for (int m = 0; m < 4; ++m) sacc[m] = z4;
#pragma unroll
        for (int ks = 0; ks < 2; ++ks)
#pragma unroll
            for (int mr = 0; mr < 4; ++mr) {
                s16x8 kf = *(const s16x8*)&Ks[cur][(mr * 16 + lr) * 64 + (((ks * 4 + lg) ^ swz) * 8)];
                sacc[mr] = __builtin_amdgcn_mfma_f32_16x16x32_bf16(kf, qf[ks], sacc[mr], 0, 0, 0);
            }

        float p[4][4];
        bool diag = (t == qt);
#pragma unroll
        for (int mr = 0; mr < 4; ++mr)
#pragma unroll
            for (int i = 0; i < 4; ++i) {
                float s = sacc[mr][i] * 0.125f;
                if (diag && (kv0 + mr * 16 + lg * 4 + i) > qrow) s = -1e30f;
                p[mr][i] = s;
            }

        float tmax = p[0][0];
#pragma unroll
        for (int mr = 0; mr < 4; ++mr)
#pragma unroll
            for (int i = 0; i < 4; ++i) tmax = fmaxf(tmax, p[mr][i]);
        tmax = fmaxf(tmax, __shfl_xor(tmax, 16));
        tmax = fmaxf(tmax, __shfl_xor(tmax, 32));

        // defer-max: only rescale when the tile max meaningfully exceeds the running max
        if (!__all(tmax <= mrun + 8.0f)) {
            float mnew = fmaxf(mrun, tmax);
            float corr = __expf(mrun - mnew);
            lrun *= corr;
#pragma unroll
            for (int m = 0; m < 4; ++m)
#pragma unroll
                for (int i = 0; i < 4; ++i) oacc[m][i] *= corr;
            mrun = mnew;
        }

        float tsum = 0.f;
#pragma unroll
        for (int mr = 0; mr < 4; ++mr)
#pragma unroll
            for (int i = 0; i < 4; ++i) {
                p[mr][i] = __expf(p[mr][i] - mrun);
                tsum += p[mr][i];
            }
        tsum += __shfl_xor(tsum, 16);
        tsum += __shfl_xor(tsum, 32);
        lrun += tsum;

        unsigned pk[4][2];
#pragma unroll
        for (int mr = 0; mr < 4; ++mr) {
            pk[mr][0] = packbf(p[mr][0], p[mr][1]);
            pk[mr][1] = packbf(p[mr][2], p[mr][3]);
        }

#pragma unroll
        for (int b2 = 0; b2 < 2; ++b2) {
            union { unsigned u[4]; s16x8 v; } pf;
#pragma unroll
            for (int r = 0; r < 4; ++r) {
                unsigned t0 = (unsigned)__shfl((int)pk[2 * b2][r & 1], srcl[r], 64);
                unsigned t1 = (unsigned)__shfl((int)pk[2 * b2 + 1][r & 1], srcl[r], 64);
                pf.u[r] = hihalf ? t1 : t0;
            }
#pragma unroll
            for (int mr = 0; mr < 4; ++mr) {
                s16x8 av = *(const s16x8*)&Vs[cur][(mr * 16 + lr) * 64 + (((b2 * 4 + lg) ^ swz) * 8)];
                oacc[mr] = __builtin_amdgcn_mfma_f32_16x16x32_bf16(av, pf.v, oacc[mr], 0, 0, 0);
            }
        }

        asm volatile("s_waitcnt vmcnt(0)" ::: "memory");  // drain this iter's prefetch
        __syncthreads();
        cur ^= 1;
    }

    float linv = 1.0f / lrun;
    bf16* yrow = yb + ((size_t)(bb * T_ + qrow)) * C_ + hh * 64;
#pragma unroll
    for (int mr = 0; mr < 4; ++mr) {
        union { unsigned short us[4]; unsigned long long u64; } w;
#pragma unroll
        for (int i = 0; i < 4; ++i)
            w.us[i] = __builtin_bit_cast(unsigned short, __float2bfloat16(oacc[mr][i] * linv));
        *(unsigned long long*)(yrow + mr * 16 + lg * 4) = w.u64;
    }
}

extern "C" void kernel_launch(void* const* d_in, const int* in_sizes, int n_in,
                              void* d_out, int out_size, void* d_ws, size_t ws_size,
                              hipStream_t stream) {
    const float* x     = (const float*)d_in[0];
    const float* Wq    = (const float*)d_in[1];
    const float* Wk    = (const float*)d_in[2];
    const float* Wv    = (const float*)d_in[3];
    const float* Wp    = (const float*)d_in[4];
    const float* bq    = (const float*)d_in[5];
    const float* bk    = (const float*)d_in[6];
    const float* bv    = (const float*)d_in[7];
    const float* bp    = (const float*)d_in[8];
    const float* ln1w  = (const float*)d_in[9];
    const float* ln1b  = (const float*)d_in[10];
    const float* ln2w  = (const float*)d_in[11];
    const float* ln2b  = (const float*)d_in[12];
    const float* W1    = (const float*)d_in[13];
    const float* b1    = (const float*)d_in[14];
    const float* W2    = (const float*)d_in[15];
    const float* b2    = (const float*)d_in[16];
    const float* lnfw  = (const float*)d_in[17];
    const float* lnfb  = (const float*)d_in[18];

    float* h = (float*)d_out;  // residual stream lives in d_out (fp32 [M,C])

    // ---- workspace carve ----
    char* base = (char*)d_ws;
    size_t off = 0;
    auto carve = [&](size_t bytes) {
        char* r = base + off;
        off += (bytes + 255) & ~(size_t)255;
        return r;
    };
    bf16*  a    = (bf16*)carve((size_t)M_ * C_ * 2);
    bf16*  qb   = (bf16*)carve((size_t)M_ * C_ * 2);
    bf16*  kb   = (bf16*)carve((size_t)M_ * C_ * 2);
    bf16*  vT   = (bf16*)carve((size_t)M_ * C_ * 2);      // [B*H*64, T]
    bf16*  yb   = (bf16*)carve((size_t)M_ * C_ * 2);
    bf16*  hid  = (bf16*)carve((size_t)M_ * FF * 2);
    float* part = (float*)carve((size_t)4 * M_ * C_ * 4); // split-K partials (32MB)
    bf16*  wt   = (bf16*)carve((size_t)WSLAB * 2);        // per-layer transposed weights (24MB)

    dim3 tb(256);

    // LN1 for layer 0 reads x directly (later layers fused into combine_ln_k)
    ln_kernel<bf16><<<M_, tb, 0, stream>>>(x, ln1w, ln1b, a);

    for (int l = 0; l < L_; ++l) {
        // per-layer weight transpose (keeps slab cache-hot for its consumers)
        transpose_all_k<<<dim3(3072, 1, 1), tb, 0, stream>>>(Wq, Wk, Wv, Wp, W1, W2, wt, l);

        // QKV fused GEMM (64x128 tile: 768 blocks = 3/CU)
        gemm_qkv_k<<<dim3(24, 32), tb, 0, stream>>>(a, wt, bq + l * C_, bk + l * C_, bv + l * C_,
                                                    qb, kb, vT);

        // flash attention (work-balanced qt remap)
        flash_k<<<dim3(16, 32), tb, 0, stream>>>(qb, kb, vT, yb);

        // out proj + residual (64x64 tile: 512 blocks = 2/CU)
        gemm_k<64, 64, EPI_RESID><<<dim3(16, 32), tb, 0, stream>>>(
            yb, C_, wt + (size_t)3 * 1048576, C_, bp + l * C_, (l == 0) ? x : h, h, C_, C_);

        // LN2 -> a
        ln_kernel<bf16><<<M_, tb, 0, stream>>>(h, ln2w + l * C_, ln2b + l * C_, a);

        // MLP up + GELU -> hid (64x128 tile: 1024 blocks, 3 resident/CU)
        gemm_k<64, 128, EPI_GELU><<<dim3(FF / 128, M_ / 64), tb, 0, stream>>>(
            a, C_, wt + (size_t)4 * 1048576, C_, b1 + l * FF, nullptr, hid, FF, C_);

        // MLP down: split-K=4, 64x128 tile (1024 blocks), then combine (+bias +residual [+next LN1])
        gemm_splitk_k<<<dim3(8, 32, 4), tb, 0, stream>>>(hid, FF, wt + (size_t)8 * 1048576, FF,
                                                         part, FF / 4);
        if (l < L_ - 1)
            combine_ln_k<4, true><<<M_, tb, 0, stream>>>(h, part, b2 + l * C_,
                                                         ln1w + (l + 1) * C_, ln1b + (l + 1) * C_, a);
        else
            combine_ln_k<4, false><<<M_, tb, 0, stream>>>(h, part, b2 + l * C_,
                                                          nullptr, nullptr, nullptr);
    }

    // final LN in place (fp32 out)
    ln_kernel<float><<<M_, tb, 0, stream>>>(h, lnfw, lnfb, h);
}

// Round 23
// 1254.594 us; speedup vs baseline: 1.0809x; 1.0809x over previous
//
#include <hip/hip_runtime.h>
#include <hip/hip_bf16.h>

#define L_ 8
#define H_ 16
#define C_ 1024
#define B_ 2
#define T_ 1024
#define M_ (B_*T_)   // 2048 rows
#define DH 64
#define FF (4*C_)    // 4096

typedef __hip_bfloat16 bf16;
typedef __attribute__((ext_vector_type(8))) short s16x8;
typedef __attribute__((ext_vector_type(4))) float f32x4;
typedef __attribute__((ext_vector_type(16))) float f32x16;

enum { EPI_QKV = 0, EPI_RESID = 1, EPI_GELU = 2, EPI_PARTIAL = 3 };

#define WSLAB 12582912  // bf16 elems per layer in wt slab: 3M qkv | 1M proj | 4M up | 4M down

__device__ __forceinline__ void gload16(const void* g, void* l) {
    __builtin_amdgcn_global_load_lds(
        (const __attribute__((address_space(1))) unsigned int*)g,
        (__attribute__((address_space(3))) unsigned int*)l, 16, 0, 0);
}

__device__ __forceinline__ unsigned short bfb(float x) {
    return __builtin_bit_cast(unsigned short, __float2bfloat16(x));
}

__device__ __forceinline__ unsigned packbf(float lo, float hi) {
    return (unsigned)bfb(lo) | ((unsigned)bfb(hi) << 16);
}

// ---------------- LayerNorm (one block per row, C=1024, 256 threads) ----------------
__device__ __forceinline__ void stv(float* p, float v) { *p = v; }
__device__ __forceinline__ void stv(bf16* p, float v) { *p = __float2bfloat16(v); }

template<typename OutT>
__global__ __launch_bounds__(256) void ln_kernel(const float* __restrict__ x,
                                                 const float* __restrict__ w,
                                                 const float* __restrict__ b,
                                                 OutT* __restrict__ out) {
    int row = blockIdx.x;
    const float* xr = x + (size_t)row * C_;
    int t = threadIdx.x;
    float4 v = *(const float4*)(xr + t * 4);

    float s = v.x + v.y + v.z + v.w;
#pragma unroll
    for (int o = 32; o >= 1; o >>= 1) s += __shfl_xor(s, o);
    __shared__ float red[4];
    int wid = t >> 6, lane = t & 63;
    if (lane == 0) red[wid] = s;
    __syncthreads();
    float mean = (red[0] + red[1] + red[2] + red[3]) * (1.0f / C_);
    __syncthreads();

    float dx = v.x - mean, dy = v.y - mean, dz = v.z - mean, dw = v.w - mean;
    float ss = dx * dx + dy * dy + dz * dz + dw * dw;
#pragma unroll
    for (int o = 32; o >= 1; o >>= 1) ss += __shfl_xor(ss, o);
    if (lane == 0) red[wid] = ss;
    __syncthreads();
    float var = (red[0] + red[1] + red[2] + red[3]) * (1.0f / C_);
    float rs = rsqrtf(var + 1e-5f);

    float4 wv = *(const float4*)(w + t * 4);
    float4 bv = *(const float4*)(b + t * 4);
    OutT* orow = out + (size_t)row * C_;
    stv(orow + t * 4 + 0, dx * rs * wv.x + bv.x);
    stv(orow + t * 4 + 1, dy * rs * wv.y + bv.y);
    stv(orow + t * 4 + 2, dz * rs * wv.z + bv.z);
    stv(orow + t * 4 + 3, dw * rs * wv.w + bv.w);
}

// ---- weight transpose v4: fp32 [Kd][Nd] -> bf16 [Nd][Kd]; 64x64 tiles ----
// NOTE: per-layer dispatch (not PRE) is deliberate — keeps each 24MB slab L2/L3-hot
// for the GEMMs that consume it immediately (PRE measured +140us, round 15).
__global__ __launch_bounds__(256) void transpose_all_k(const float* __restrict__ Wq,
                                                       const float* __restrict__ Wk,
                                                       const float* __restrict__ Wv,
                                                       const float* __restrict__ Wp,
                                                       const float* __restrict__ W1,
                                                       const float* __restrict__ W2,
                                                       bf16* __restrict__ wt, int l0) {
    int layer = l0 + blockIdx.z;
    bf16* slab = wt + (size_t)blockIdx.z * WSLAB;
    int idx = blockIdx.x;  // 3072 tiles of 64x64 per layer
    const float* W; bf16* dst; int Kd, Nd;
    if (idx < 768) {
        int z = idx >> 8;
        W = ((z == 0) ? Wq : (z == 1) ? Wk : Wv) + (size_t)layer * C_ * C_;
        dst = slab + (size_t)z * 1048576; Kd = C_; Nd = C_; idx &= 255;
    } else if (idx < 1024) {
        W = Wp + (size_t)layer * C_ * C_;
        dst = slab + (size_t)3 * 1048576; Kd = C_; Nd = C_; idx -= 768;
    } else if (idx < 2048) {
        W = W1 + (size_t)layer * C_ * FF;
        dst = slab + (size_t)4 * 1048576; Kd = C_; Nd = FF; idx -= 1024;
    } else {
        W = W2 + (size_t)layer * FF * C_;
        dst = slab + (size_t)8 * 1048576; Kd = FF; Nd = C_; idx -= 2048;
    }
    int ntx = Nd >> 6;
    int gx = (idx & (ntx - 1)) << 6, gy = (idx / ntx) << 6;  // gx over Nd, gy over Kd

    __shared__ __align__(8) unsigned short tile[64][66];  // 132B row stride
    int tid = threadIdx.x, wid = tid >> 6, lane = tid & 63;
#pragma unroll
    for (int i = 0; i < 4; ++i) {
        int s = i * 256 + tid, r = s >> 4, c4 = (s & 15) * 4;
        float4 v = *(const float4*)(W + (size_t)(gy + r) * Nd + gx + c4);
        union { unsigned short us[4]; unsigned long long u64; } pk_;
        pk_.us[0] = bfb(v.x); pk_.us[1] = bfb(v.y); pk_.us[2] = bfb(v.z); pk_.us[3] = bfb(v.w);
        *(unsigned long long*)&tile[r][c4] = pk_.u64;
    }
    __syncthreads();
    int k0 = (lane & 7) * 8;
#pragma unroll
    for (int i = 0; i < 2; ++i) {
        int n = wid * 16 + (lane >> 3) + 8 * i;
        union { unsigned short us[8]; s16x8 v; } w;
#pragma unroll
        for (int j = 0; j < 8; ++j) w.us[j] = tile[k0 + j][n];
        *(s16x8*)&dst[(size_t)(gx + n) * Kd + gy + k0] = w.v;
    }
}

// ------- MFMA GEMM tile: 32x32x16 bf16, BK=64, dbuf LDS (stage t+1 || compute t), XOR swizzle -------
// 256 threads = 2x2 waves; wave tile (BM/2)x(BN/2).
template<int BM, int BN, int EPI>
__device__ __forceinline__ void gemm_tile(const bf16* __restrict__ A_, int lda,
                                          const bf16* __restrict__ Bt_, int ldb,
                                          const float* __restrict__ bias,
                                          const float* __restrict__ bias2,
                                          const float* __restrict__ bias3,
                                          const float* __restrict__ rsrc,
                                          void* __restrict__ C0, void* __restrict__ C1,
                                          void* __restrict__ C2, int ldc,
                                          int K, int bm0, int bn0) {
    constexpr int WM = BM / 2, WN = BN / 2, MR = WM / 32, NR = WN / 32;
    __shared__ __align__(16) short As[2][BM * 64];
    __shared__ __align__(16) short Bs[2][BN * 64];
    const short* Ap = (const short*)A_;
    const short* Bp = (const short*)Bt_;

    int tid = threadIdx.x;
    int wid = tid >> 6, lane = tid & 63;
    int la = lane & 31, lk = lane >> 5;     // frag row, k-half
    int wr = wid >> 1, wc = wid & 1;
    int sa = la & 7;                         // read-side swizzle key (row&7)

    auto stage = [&](int bf, int k0) {
        // SOURCE-side swizzle, linear LDS dest (rule #21)
#pragma unroll
        for (int i = 0; i < BM / 32; ++i) {
            int slot = i * 256 + tid;
            int row = slot >> 3, cs = (slot & 7) ^ (row & 7);
            gload16(Ap + (size_t)(bm0 + row) * lda + (k0 + cs * 8),
                    &As[bf][(i * 256 + wid * 64) * 8]);
        }
#pragma unroll
        for (int i = 0; i < BN / 32; ++i) {
            int slot = i * 256 + tid;
            int row = slot >> 3, cs = (slot & 7) ^ (row & 7);
            gload16(Bp + (size_t)(bn0 + row) * ldb + (k0 + cs * 8),
                    &Bs[bf][(i * 256 + wid * 64) * 8]);
        }
    };

    f32x16 acc[MR][NR];
#pragma unroll
    for (int m = 0; m < MR; ++m)
#pragma unroll
        for (int n = 0; n < NR; ++n)
#pragma unroll
            for (int i = 0; i < 16; ++i) acc[m][n][i] = 0.f;

    stage(0, 0);
    asm volatile("s_waitcnt vmcnt(0)" ::: "memory");
    __syncthreads();
    int cur = 0;

    for (int k0 = 0; k0 < K; k0 += 64) {
        if (k0 + 64 < K) stage(cur ^ 1, k0 + 64);  // prefetch next tile (overlaps compute)

        s16x8 af[MR][4], bfv[NR][4];
#pragma unroll
        for (int m = 0; m < MR; ++m)
#pragma unroll
            for (int kk = 0; kk < 4; ++kk)
                af[m][kk] = *(const s16x8*)&As[cur][(wr * WM + m * 32 + la) * 64 +
                                                   (((kk * 2 + lk) ^ sa) * 8)];
#pragma unroll
        for (int n = 0; n < NR; ++n)
#pragma unroll
            for (int kk = 0; kk < 4; ++kk)
                bfv[n][kk] = *(const s16x8*)&Bs[cur][(wc * WN + n * 32 + la) * 64 +
                                                    (((kk * 2 + lk) ^ sa) * 8)];
#pragma unroll
        for (int m = 0; m < MR; ++m)
#pragma unroll
            for (int n = 0; n < NR; ++n)
#pragma unroll
                for (int kk = 0; kk < 4; ++kk)
                    acc[m][n] = __builtin_amdgcn_mfma_f32_32x32x16_bf16(af[m][kk], bfv[n][kk],
                                                                        acc[m][n], 0, 0, 0);

        asm volatile("s_waitcnt vmcnt(0)" ::: "memory");  // stage(t+1) landed
        __syncthreads();
        cur ^= 1;
    }

    // epilogue: 32x32 C/D layout col=lane&31, row=(i&3)+8*(i>>2)+4*(lane>>5)  [verified m74/m101]
#pragma unroll
    for (int m = 0; m < MR; ++m)
#pragma unroll
        for (int n = 0; n < NR; ++n)
#pragma unroll
            for (int i = 0; i < 16; ++i) {
                int gm = bm0 + wr * WM + m * 32 + (i & 3) + 8 * (i >> 2) + 4 * lk;
                int gn = bn0 + wc * WN + n * 32 + la;
                float v = acc[m][n][i];
                if constexpr (EPI == EPI_QKV) {
                    if (gn < 1024) {
                        ((bf16*)C0)[(size_t)gm * C_ + gn] = __float2bfloat16(v + bias[gn]);
                    } else if (gn < 2048) {
                        ((bf16*)C1)[(size_t)gm * C_ + (gn - 1024)] =
                            __float2bfloat16(v + bias2[gn - 1024]);
                    } else {
                        int d = gn - 2048, bb = gm >> 10, tt = gm & 1023;
                        ((bf16*)C2)[((size_t)(bb * 1024 + d)) * T_ + tt] =
                            __float2bfloat16(v + bias3[d]);
                    }
                } else if constexpr (EPI == EPI_RESID) {
                    // read residual from rsrc (x for layer 0, h otherwise), write h
                    ((float*)C0)[(size_t)gm * ldc + gn] =
                        rsrc[(size_t)gm * ldc + gn] + v + bias[gn];
                } else if constexpr (EPI == EPI_GELU) {
                    float xg = v + bias[gn];
                    float g = 0.5f * xg * (1.0f + erff(xg * 0.70710678118654752f));
                    ((bf16*)C0)[(size_t)gm * ldc + gn] = __float2bfloat16(g);
                } else if constexpr (EPI == EPI_PARTIAL) {
                    ((float*)C0)[(size_t)gm * ldc + gn] = v;
                }
            }
}

template<int BM, int BN, int EPI>
__global__ __launch_bounds__(256) void gemm_k(const bf16* A, int lda, const bf16* Bt, int ldb,
                                              const float* bias, const float* rsrc,
                                              void* C0, int ldc, int K) {
    gemm_tile<BM, BN, EPI>(A, lda, Bt, ldb, bias, nullptr, nullptr, rsrc,
                           C0, nullptr, nullptr, ldc, K, blockIdx.y * BM, blockIdx.x * BN);
}

// QKV: 64x128 tile -> grid 24x32 = 768 blocks = 3/CU
__global__ __launch_bounds__(256) void gemm_qkv_k(const bf16* a, const bf16* wt,
                                                  const float* bq, const float* bk, const float* bv,
                                                  bf16* qb, bf16* kb, bf16* vT) {
    gemm_tile<64, 128, EPI_QKV>(a, C_, wt, C_, bq, bk, bv, nullptr, qb, kb, vT, 0, C_,
                                blockIdx.y * 64, blockIdx.x * 128);
}

// split-K over blockIdx.z (4 slices of FF/4, 128x128 tile -> 512 blocks = 2/CU: measured sweet spot)
__global__ __launch_bounds__(256) void gemm_splitk_k(const bf16* A, int lda, const bf16* Bt, int ldb,
                                                     float* part, int Ksl) {
    int z = blockIdx.z;
    gemm_tile<128, 128, EPI_PARTIAL>(A + (size_t)z * Ksl, lda, Bt + (size_t)z * Ksl, ldb,
                                     nullptr, nullptr, nullptr, nullptr,
                                     part + (size_t)z * M_ * C_, nullptr, nullptr, C_, Ksl,
                                     blockIdx.y * 128, blockIdx.x * 128);
}

// ---- split-K combine (+bias +residual into h), optionally fused next-layer LN1 -> a ----
template<int NPART, bool LN>
__global__ __launch_bounds__(256) void combine_ln_k(float* __restrict__ h,
                                                    const float* __restrict__ part,
                                                    const float* __restrict__ bias,
                                                    const float* __restrict__ lw,
                                                    const float* __restrict__ lb,
                                                    bf16* __restrict__ aout) {
    int row = blockIdx.x, t = threadIdx.x;
    float4 hv = ((const float4*)(h + (size_t)row * C_))[t];
    float4 bb = ((const float4*)bias)[t];
    hv.x += bb.x; hv.y += bb.y; hv.z += bb.z; hv.w += bb.w;
#pragma unroll
    for (int z = 0; z < NPART; ++z) {
        float4 p = ((const float4*)(part + (size_t)z * M_ * C_ + (size_t)row * C_))[t];
        hv.x += p.x; hv.y += p.y; hv.z += p.z; hv.w += p.w;
    }
    ((float4*)(h + (size_t)row * C_))[t] = hv;

    if constexpr (LN) {
        float s = hv.x + hv.y + hv.z + hv.w;
#pragma unroll
        for (int o = 32; o >= 1; o >>= 1) s += __shfl_xor(s, o);
        __shared__ float red[4];
        int wid = t >> 6, lane = t & 63;
        if (lane == 0) red[wid] = s;
        __syncthreads();
        float mean = (red[0] + red[1] + red[2] + red[3]) * (1.0f / C_);
        __syncthreads();
        float dx = hv.x - mean, dy = hv.y - mean, dz = hv.z - mean, dw = hv.w - mean;
        float ss = dx * dx + dy * dy + dz * dz + dw * dw;
#pragma unroll
        for (int o = 32; o >= 1; o >>= 1) ss += __shfl_xor(ss, o);
        if (lane == 0) red[wid] = ss;
        __syncthreads();
        float var = (red[0] + red[1] + red[2] + red[3]) * (1.0f / C_);
        float rs = rsqrtf(var + 1e-5f);
        float4 wv = ((const float4*)lw)[t];
        float4 bv = ((const float4*)lb)[t];
        bf16* ar = aout + (size_t)row * C_;
        ar[t * 4 + 0] = __float2bfloat16(dx * rs * wv.x + bv.x);
        ar[t * 4 + 1] = __float2bfloat16(dy * rs * wv.y + bv.y);
        ar[t * 4 + 2] = __float2bfloat16(dz * rs * wv.z + bv.z);
        ar[t * 4 + 3] = __float2bfloat16(dw * rs * wv.w + bv.w);
    }
}

// ---------------- Flash attention: one block per (64-q tile, head pair) ----------------
// defer-max (T13). Work-balanced qt remap: co-resident blocks f and f+256 (same x,
// y vs y+16) get qt = x and 15-x, so each CU's pair sums to 17 tile-steps.
__global__ __launch_bounds__(256) void flash_k(const bf16* __restrict__ qb,
                                               const bf16* __restrict__ kb,
                                               const bf16* __restrict__ vT,
                                               bf16* __restrict__ yb) {
    int pair = blockIdx.y;
    int qt = (pair >= 16) ? (15 - blockIdx.x) : blockIdx.x;
    int bb = pair >> 4, hh = pair & 15;
    __shared__ __align__(16) short Ks[2][64 * 64];
    __shared__ __align__(16) short Vs[2][64 * 64];

    int tid = threadIdx.x, wid = tid >> 6, lane = tid & 63, lr = lane & 15, lg = lane >> 4;
    int qrow = qt * 64 + wid * 16 + lr;

    const short* qp = (const short*)qb + ((size_t)(bb * T_ + qrow)) * C_ + hh * 64;
    s16x8 qf[2];
    qf[0] = *(const s16x8*)(qp + lg * 8);
    qf[1] = *(const s16x8*)(qp + 32 + lg * 8);

    const short* kbase = (const short*)kb + ((size_t)bb * T_) * C_ + hh * 64;  // row kv, stride C_
    const short* vbase = (const short*)vT + ((size_t)pair * 64) * T_;          // row d, stride T_

    auto stage = [&](int bf, int t) {
        int kv0 = t * 64;
#pragma unroll
        for (int i = 0; i < 2; ++i) {
            int slot = i * 256 + tid;
            int row = slot >> 3, cs = (slot & 7) ^ (row & 7);
            gload16(kbase + (size_t)(kv0 + row) * C_ + cs * 8, &Ks[bf][(i * 256 + wid * 64) * 8]);
        }
#pragma unroll
        for (int i = 0; i < 2; ++i) {
            int slot = i * 256 + tid;
            int row = slot >> 3, cs = (slot & 7) ^ (row & 7);
            gload16(vbase + (size_t)row * T_ + kv0 + cs * 8, &Vs[bf][(i * 256 + wid * 64) * 8]);
        }
    };

    f32x4 oacc[4];
    const f32x4 z4 = {0.f, 0.f, 0.f, 0.f};
#pragma unroll
    for (int m = 0; m < 4; ++m) oacc[m] = z4;
    float mrun = -INFINITY, lrun = 0.f;

    int srcl[4];
#pragma unroll
    for (int r = 0; r < 4; ++r) srcl[r] = ((((lg << 3) + 2 * r) & 15) >> 2) * 16 + lr;
    bool hihalf = lg >= 2;
    int swz = lr & 7;

    stage(0, 0);
    asm volatile("s_waitcnt vmcnt(0)" ::: "memory");
    __syncthreads();
    int cur = 0;

    for (int t = 0; t <= qt; ++t) {
        int kv0 = t * 64;
        if (t < qt) stage(cur ^ 1, t + 1);  // prefetch next tile into the other buffer

        f32x4 sacc[4];
#pragma unroll
        for (int m = 0; m < 4; ++m) sacc[m] = z4;
#pragma unroll
        for (int ks = 0; ks < 2; ++ks)
#pragma unroll
            for (int mr = 0; mr < 4; ++mr) {
                s16x8 kf = *(const s16x8*)&Ks[cur][(mr * 16 + lr) * 64 + (((ks * 4 + lg) ^ swz) * 8)];
                sacc[mr] = __builtin_amdgcn_mfma_f32_16x16x32_bf16(kf, qf[ks], sacc[mr], 0, 0, 0);
            }

        float p[4][4];
        bool diag = (t == qt);
#pragma unroll
        for (int mr = 0; mr < 4; ++mr)
#pragma unroll
            for (int i = 0; i < 4; ++i) {
                float s = sacc[mr][i] * 0.125f;
                if (diag && (kv0 + mr * 16 + lg * 4 + i) > qrow) s = -1e30f;
                p[mr][i] = s;
            }

        float tmax = p[0][0];
#pragma unroll
        for (int mr = 0; mr < 4; ++mr)
#pragma unroll
            for (int i = 0; i < 4; ++i) tmax = fmaxf(tmax, p[mr][i]);
        tmax = fmaxf(tmax, __shfl_xor(tmax, 16));
        tmax = fmaxf(tmax, __shfl_xor(tmax, 32));

        // defer-max: only rescale when the tile max meaningfully exceeds the running max
        if (!__all(tmax <= mrun + 8.0f)) {
            float mnew = fmaxf(mrun, tmax);
            float corr = __expf(mrun - mnew);
            lrun *= corr;
#pragma unroll
            for (int m = 0; m < 4; ++m)
#pragma unroll
                for (int i = 0; i < 4; ++i) oacc[m][i] *= corr;
            mrun = mnew;
        }

        float tsum = 0.f;
#pragma unroll
        for (int mr = 0; mr < 4; ++mr)
#pragma unroll
            for (int i = 0; i < 4; ++i) {
                p[mr][i] = __expf(p[mr][i] - mrun);
                tsum += p[mr][i];
            }
        tsum += __shfl_xor(tsum, 16);
        tsum += __shfl_xor(tsum, 32);
        lrun += tsum;

        unsigned pk[4][2];
#pragma unroll
        for (int mr = 0; mr < 4; ++mr) {
            pk[mr][0] = packbf(p[mr][0], p[mr][1]);
            pk[mr][1] = packbf(p[mr][2], p[mr][3]);
        }

#pragma unroll
        for (int b2 = 0; b2 < 2; ++b2) {
            union { unsigned u[4]; s16x8 v; } pf;
#pragma unroll
            for (int r = 0; r < 4; ++r) {
                unsigned t0 = (unsigned)__shfl((int)pk[2 * b2][r & 1], srcl[r], 64);
                unsigned t1 = (unsigned)__shfl((int)pk[2 * b2 + 1][r & 1], srcl[r], 64);
                pf.u[r] = hihalf ? t1 : t0;
            }
#pragma unroll
            for (int mr = 0; mr < 4; ++mr) {
                s16x8 av = *(const s16x8*)&Vs[cur][(mr * 16 + lr) * 64 + (((b2 * 4 + lg) ^ swz) * 8)];
                oacc[mr] = __builtin_amdgcn_mfma_f32_16x16x32_bf16(av, pf.v, oacc[mr], 0, 0, 0);
            }
        }

        asm volatile("s_waitcnt vmcnt(0)" ::: "memory");  // drain this iter's prefetch
        __syncthreads();
        cur ^= 1;
    }

    float linv = 1.0f / lrun;
    bf16* yrow = yb + ((size_t)(bb * T_ + qrow)) * C_ + hh * 64;
#pragma unroll
    for (int mr = 0; mr < 4; ++mr) {
        union { unsigned short us[4]; unsigned long long u64; } w;
#pragma unroll
        for (int i = 0; i < 4; ++i)
            w.us[i] = __builtin_bit_cast(unsigned short, __float2bfloat16(oacc[mr][i] * linv));
        *(unsigned long long*)(yrow + mr * 16 + lg * 4) = w.u64;
    }
}

extern "C" void kernel_launch(void* const* d_in, const int* in_sizes, int n_in,
                              void* d_out, int out_size, void* d_ws, size_t ws_size,
                              hipStream_t stream) {
    const float* x     = (const float*)d_in[0];
    const float* Wq    = (const float*)d_in[1];
    const float* Wk    = (const float*)d_in[2];
    const float* Wv    = (const float*)d_in[3];
    const float* Wp    = (const float*)d_in[4];
    const float* bq    = (const float*)d_in[5];
    const float* bk    = (const float*)d_in[6];
    const float* bv    = (const float*)d_in[7];
    const float* bp    = (const float*)d_in[8];
    const float* ln1w  = (const float*)d_in[9];
    const float* ln1b  = (const float*)d_in[10];
    const float* ln2w  = (const float*)d_in[11];
    const float* ln2b  = (const float*)d_in[12];
    const float* W1    = (const float*)d_in[13];
    const float* b1    = (const float*)d_in[14];
    const float* W2    = (const float*)d_in[15];
    const float* b2    = (const float*)d_in[16];
    const float* lnfw  = (const float*)d_in[17];
    const float* lnfb  = (const float*)d_in[18];

    float* h = (float*)d_out;  // residual stream lives in d_out (fp32 [M,C])

    // ---- workspace carve ----
    char* base = (char*)d_ws;
    size_t off = 0;
    auto carve = [&](size_t bytes) {
        char* r = base + off;
        off += (bytes + 255) & ~(size_t)255;
        return r;
    };
    bf16*  a    = (bf16*)carve((size_t)M_ * C_ * 2);
    bf16*  qb   = (bf16*)carve((size_t)M_ * C_ * 2);
    bf16*  kb   = (bf16*)carve((size_t)M_ * C_ * 2);
    bf16*  vT   = (bf16*)carve((size_t)M_ * C_ * 2);      // [B*H*64, T]
    bf16*  yb   = (bf16*)carve((size_t)M_ * C_ * 2);
    bf16*  hid  = (bf16*)carve((size_t)M_ * FF * 2);
    float* part = (float*)carve((size_t)4 * M_ * C_ * 4); // split-K partials (32MB)
    bf16*  wt   = (bf16*)carve((size_t)WSLAB * 2);        // per-layer transposed weights (24MB)

    dim3 tb(256);

    // LN1 for layer 0 reads x directly (later layers fused into combine_ln_k)
    ln_kernel<bf16><<<M_, tb, 0, stream>>>(x, ln1w, ln1b, a);

    for (int l = 0; l < L_; ++l) {
        // per-layer weight transpose (keeps slab cache-hot for its consumers)
        transpose_all_k<<<dim3(3072, 1, 1), tb, 0, stream>>>(Wq, Wk, Wv, Wp, W1, W2, wt, l);

        // QKV fused GEMM (64x128 tile: 768 blocks = 3/CU)
        gemm_qkv_k<<<dim3(24, 32), tb, 0, stream>>>(a, wt, bq + l * C_, bk + l * C_, bv + l * C_,
                                                    qb, kb, vT);

        // flash attention (work-balanced qt remap)
        flash_k<<<dim3(16, 32), tb, 0, stream>>>(qb, kb, vT, yb);

        // out proj + residual (64x64 tile: 512 blocks = 2/CU)
        gemm_k<64, 64, EPI_RESID><<<dim3(16, 32), tb, 0, stream>>>(
            yb, C_, wt + (size_t)3 * 1048576, C_, bp + l * C_, (l == 0) ? x : h, h, C_, C_);

        // LN2 -> a
        ln_kernel<bf16><<<M_, tb, 0, stream>>>(h, ln2w + l * C_, ln2b + l * C_, a);

        // MLP up + GELU -> hid (128x128 tile: 512 blocks = 2/CU, measured sweet spot)
        gemm_k<128, 128, EPI_GELU><<<dim3(FF / 128, M_ / 128), tb, 0, stream>>>(
            a, C_, wt + (size_t)4 * 1048576, C_, b1 + l * FF, nullptr, hid, FF, C_);

        // MLP down: split-K=4 partials (128x128, 512 blocks = 2/CU), then combine
        gemm_splitk_k<<<dim3(8, 16, 4), tb, 0, stream>>>(hid, FF, wt + (size_t)8 * 1048576, FF,
                                                         part, FF / 4);
        if (l < L_ - 1)
            combine_ln_k<4, true><<<M_, tb, 0, stream>>>(h, part, b2 + l * C_,
                                                         ln1w + (l + 1) * C_, ln1b + (l + 1) * C_, a);
        else
            combine_ln_k<4, false><<<M_, tb, 0, stream>>>(h, part, b2 + l * C_,
                                                          nullptr, nullptr, nullptr);
    }

    // final LN in place (fp32 out)
    ln_kernel<float><<<M_, tb, 0, stream>>>(h, lnfw, lnfb, h);
}

// Round 24
// 1222.637 us; speedup vs baseline: 1.1091x; 1.0261x over previous
//
#include <hip/hip_runtime.h>
#include <hip/hip_bf16.h>

#define L_ 8
#define H_ 16
#define C_ 1024
#define B_ 2
#define T_ 1024
#define M_ (B_*T_)   // 2048 rows
#define DH 64
#define FF (4*C_)    // 4096

typedef __hip_bfloat16 bf16;
typedef __attribute__((ext_vector_type(8))) short s16x8;
typedef __attribute__((ext_vector_type(4))) float f32x4;
typedef __attribute__((ext_vector_type(16))) float f32x16;

enum { EPI_QKV = 0, EPI_RESID = 1, EPI_GELU = 2, EPI_PARTIAL = 3 };

#define WSLAB 12582912  // bf16 elems per layer in wt slab: 3M qkv | 1M proj | 4M up | 4M down

__device__ __forceinline__ void gload16(const void* g, void* l) {
    __builtin_amdgcn_global_load_lds(
        (const __attribute__((address_space(1))) unsigned int*)g,
        (__attribute__((address_space(3))) unsigned int*)l, 16, 0, 0);
}

__device__ __forceinline__ unsigned short bfb(float x) {
    return __builtin_bit_cast(unsigned short, __float2bfloat16(x));
}

__device__ __forceinline__ float bf2f(unsigned short u) {
    return __builtin_bit_cast(float, (unsigned)u << 16);
}

__device__ __forceinline__ unsigned packbf(float lo, float hi) {
    return (unsigned)bfb(lo) | ((unsigned)bfb(hi) << 16);
}

// ---------------- LayerNorm (one block per row, C=1024, 256 threads) ----------------
__device__ __forceinline__ void stv(float* p, float v) { *p = v; }
__device__ __forceinline__ void stv(bf16* p, float v) { *p = __float2bfloat16(v); }

template<typename OutT>
__global__ __launch_bounds__(256) void ln_kernel(const float* __restrict__ x,
                                                 const float* __restrict__ w,
                                                 const float* __restrict__ b,
                                                 OutT* __restrict__ out) {
    int row = blockIdx.x;
    const float* xr = x + (size_t)row * C_;
    int t = threadIdx.x;
    float4 v = *(const float4*)(xr + t * 4);

    float s = v.x + v.y + v.z + v.w;
#pragma unroll
    for (int o = 32; o >= 1; o >>= 1) s += __shfl_xor(s, o);
    __shared__ float red[4];
    int wid = t >> 6, lane = t & 63;
    if (lane == 0) red[wid] = s;
    __syncthreads();
    float mean = (red[0] + red[1] + red[2] + red[3]) * (1.0f / C_);
    __syncthreads();

    float dx = v.x - mean, dy = v.y - mean, dz = v.z - mean, dw = v.w - mean;
    float ss = dx * dx + dy * dy + dz * dz + dw * dw;
#pragma unroll
    for (int o = 32; o >= 1; o >>= 1) ss += __shfl_xor(ss, o);
    if (lane == 0) red[wid] = ss;
    __syncthreads();
    float var = (red[0] + red[1] + red[2] + red[3]) * (1.0f / C_);
    float rs = rsqrtf(var + 1e-5f);

    float4 wv = *(const float4*)(w + t * 4);
    float4 bv = *(const float4*)(b + t * 4);
    OutT* orow = out + (size_t)row * C_;
    stv(orow + t * 4 + 0, dx * rs * wv.x + bv.x);
    stv(orow + t * 4 + 1, dy * rs * wv.y + bv.y);
    stv(orow + t * 4 + 2, dz * rs * wv.z + bv.z);
    stv(orow + t * 4 + 3, dw * rs * wv.w + bv.w);
}

// ---- weight transpose v4: fp32 [Kd][Nd] -> bf16 [Nd][Kd]; 64x64 tiles ----
// NOTE: per-layer dispatch (not PRE) is deliberate — keeps each 24MB slab L2/L3-hot
// for the GEMMs that consume it immediately (PRE measured +140us, round 15).
__global__ __launch_bounds__(256) void transpose_all_k(const float* __restrict__ Wq,
                                                       const float* __restrict__ Wk,
                                                       const float* __restrict__ Wv,
                                                       const float* __restrict__ Wp,
                                                       const float* __restrict__ W1,
                                                       const float* __restrict__ W2,
                                                       bf16* __restrict__ wt, int l0) {
    int layer = l0 + blockIdx.z;
    bf16* slab = wt + (size_t)blockIdx.z * WSLAB;
    int idx = blockIdx.x;  // 3072 tiles of 64x64 per layer
    const float* W; bf16* dst; int Kd, Nd;
    if (idx < 768) {
        int z = idx >> 8;
        W = ((z == 0) ? Wq : (z == 1) ? Wk : Wv) + (size_t)layer * C_ * C_;
        dst = slab + (size_t)z * 1048576; Kd = C_; Nd = C_; idx &= 255;
    } else if (idx < 1024) {
        W = Wp + (size_t)layer * C_ * C_;
        dst = slab + (size_t)3 * 1048576; Kd = C_; Nd = C_; idx -= 768;
    } else if (idx < 2048) {
        W = W1 + (size_t)layer * C_ * FF;
        dst = slab + (size_t)4 * 1048576; Kd = C_; Nd = FF; idx -= 1024;
    } else {
        W = W2 + (size_t)layer * FF * C_;
        dst = slab + (size_t)8 * 1048576; Kd = FF; Nd = C_; idx -= 2048;
    }
    int ntx = Nd >> 6;
    int gx = (idx & (ntx - 1)) << 6, gy = (idx / ntx) << 6;  // gx over Nd, gy over Kd

    __shared__ __align__(8) unsigned short tile[64][66];  // 132B row stride
    int tid = threadIdx.x, wid = tid >> 6, lane = tid & 63;
#pragma unroll
    for (int i = 0; i < 4; ++i) {
        int s = i * 256 + tid, r = s >> 4, c4 = (s & 15) * 4;
        float4 v = *(const float4*)(W + (size_t)(gy + r) * Nd + gx + c4);
        union { unsigned short us[4]; unsigned long long u64; } pk_;
        pk_.us[0] = bfb(v.x); pk_.us[1] = bfb(v.y); pk_.us[2] = bfb(v.z); pk_.us[3] = bfb(v.w);
        *(unsigned long long*)&tile[r][c4] = pk_.u64;
    }
    __syncthreads();
    int k0 = (lane & 7) * 8;
#pragma unroll
    for (int i = 0; i < 2; ++i) {
        int n = wid * 16 + (lane >> 3) + 8 * i;
        union { unsigned short us[8]; s16x8 v; } w;
#pragma unroll
        for (int j = 0; j < 8; ++j) w.us[j] = tile[k0 + j][n];
        *(s16x8*)&dst[(size_t)(gx + n) * Kd + gy + k0] = w.v;
    }
}

// ------- MFMA GEMM tile: 32x32x16 bf16, BK=64, dbuf LDS (stage t+1 || compute t), XOR swizzle -------
// 256 threads = 2x2 waves; wave tile (BM/2)x(BN/2).
template<int BM, int BN, int EPI>
__device__ __forceinline__ void gemm_tile(const bf16* __restrict__ A_, int lda,
                                          const bf16* __restrict__ Bt_, int ldb,
                                          const float* __restrict__ bias,
                                          const float* __restrict__ bias2,
                                          const float* __restrict__ bias3,
                                          const float* __restrict__ rsrc,
                                          void* __restrict__ C0, void* __restrict__ C1,
                                          void* __restrict__ C2, int ldc,
                                          int K, int bm0, int bn0) {
    constexpr int WM = BM / 2, WN = BN / 2, MR = WM / 32, NR = WN / 32;
    __shared__ __align__(16) short As[2][BM * 64];
    __shared__ __align__(16) short Bs[2][BN * 64];
    const short* Ap = (const short*)A_;
    const short* Bp = (const short*)Bt_;

    int tid = threadIdx.x;
    int wid = tid >> 6, lane = tid & 63;
    int la = lane & 31, lk = lane >> 5;     // frag row, k-half
    int wr = wid >> 1, wc = wid & 1;
    int sa = la & 7;                         // read-side swizzle key (row&7)

    auto stage = [&](int bf, int k0) {
        // SOURCE-side swizzle, linear LDS dest (rule #21)
#pragma unroll
        for (int i = 0; i < BM / 32; ++i) {
            int slot = i * 256 + tid;
            int row = slot >> 3, cs = (slot & 7) ^ (row & 7);
            gload16(Ap + (size_t)(bm0 + row) * lda + (k0 + cs * 8),
                    &As[bf][(i * 256 + wid * 64) * 8]);
        }
#pragma unroll
        for (int i = 0; i < BN / 32; ++i) {
            int slot = i * 256 + tid;
            int row = slot >> 3, cs = (slot & 7) ^ (row & 7);
            gload16(Bp + (size_t)(bn0 + row) * ldb + (k0 + cs * 8),
                    &Bs[bf][(i * 256 + wid * 64) * 8]);
        }
    };

    f32x16 acc[MR][NR];
#pragma unroll
    for (int m = 0; m < MR; ++m)
#pragma unroll
        for (int n = 0; n < NR; ++n)
#pragma unroll
            for (int i = 0; i < 16; ++i) acc[m][n][i] = 0.f;

    stage(0, 0);
    asm volatile("s_waitcnt vmcnt(0)" ::: "memory");
    __syncthreads();
    int cur = 0;

    for (int k0 = 0; k0 < K; k0 += 64) {
        if (k0 + 64 < K) stage(cur ^ 1, k0 + 64);  // prefetch next tile (overlaps compute)

        s16x8 af[MR][4], bfv[NR][4];
#pragma unroll
        for (int m = 0; m < MR; ++m)
#pragma unroll
            for (int kk = 0; kk < 4; ++kk)
                af[m][kk] = *(const s16x8*)&As[cur][(wr * WM + m * 32 + la) * 64 +
                                                   (((kk * 2 + lk) ^ sa) * 8)];
#pragma unroll
        for (int n = 0; n < NR; ++n)
#pragma unroll
            for (int kk = 0; kk < 4; ++kk)
                bfv[n][kk] = *(const s16x8*)&Bs[cur][(wc * WN + n * 32 + la) * 64 +
                                                    (((kk * 2 + lk) ^ sa) * 8)];
#pragma unroll
        for (int m = 0; m < MR; ++m)
#pragma unroll
            for (int n = 0; n < NR; ++n)
#pragma unroll
                for (int kk = 0; kk < 4; ++kk)
                    acc[m][n] = __builtin_amdgcn_mfma_f32_32x32x16_bf16(af[m][kk], bfv[n][kk],
                                                                        acc[m][n], 0, 0, 0);

        asm volatile("s_waitcnt vmcnt(0)" ::: "memory");  // stage(t+1) landed
        __syncthreads();
        cur ^= 1;
    }

    // epilogue: 32x32 C/D layout col=lane&31, row=(i&3)+8*(i>>2)+4*(lane>>5)  [verified m74/m101]
#pragma unroll
    for (int m = 0; m < MR; ++m)
#pragma unroll
        for (int n = 0; n < NR; ++n)
#pragma unroll
            for (int i = 0; i < 16; ++i) {
                int gm = bm0 + wr * WM + m * 32 + (i & 3) + 8 * (i >> 2) + 4 * lk;
                int gn = bn0 + wc * WN + n * 32 + la;
                float v = acc[m][n][i];
                if constexpr (EPI == EPI_QKV) {
                    if (gn < 1024) {
                        ((bf16*)C0)[(size_t)gm * C_ + gn] = __float2bfloat16(v + bias[gn]);
                    } else if (gn < 2048) {
                        ((bf16*)C1)[(size_t)gm * C_ + (gn - 1024)] =
                            __float2bfloat16(v + bias2[gn - 1024]);
                    } else {
                        int d = gn - 2048, bb = gm >> 10, tt = gm & 1023;
                        ((bf16*)C2)[((size_t)(bb * 1024 + d)) * T_ + tt] =
                            __float2bfloat16(v + bias3[d]);
                    }
                } else if constexpr (EPI == EPI_RESID) {
                    // read residual from rsrc (x for layer 0, h otherwise), write h
                    ((float*)C0)[(size_t)gm * ldc + gn] =
                        rsrc[(size_t)gm * ldc + gn] + v + bias[gn];
                } else if constexpr (EPI == EPI_GELU) {
                    float xg = v + bias[gn];
                    float g = 0.5f * xg * (1.0f + erff(xg * 0.70710678118654752f));
                    ((bf16*)C0)[(size_t)gm * ldc + gn] = __float2bfloat16(g);
                } else if constexpr (EPI == EPI_PARTIAL) {
                    // bf16 partials: halves split-K partial HBM round-trip
                    ((bf16*)C0)[(size_t)gm * ldc + gn] = __float2bfloat16(v);
                }
            }
}

template<int BM, int BN, int EPI>
__global__ __launch_bounds__(256) void gemm_k(const bf16* A, int lda, const bf16* Bt, int ldb,
                                              const float* bias, const float* rsrc,
                                              void* C0, int ldc, int K) {
    gemm_tile<BM, BN, EPI>(A, lda, Bt, ldb, bias, nullptr, nullptr, rsrc,
                           C0, nullptr, nullptr, ldc, K, blockIdx.y * BM, blockIdx.x * BN);
}

// QKV: 64x128 tile -> grid 24x32 = 768 blocks = 3/CU
__global__ __launch_bounds__(256) void gemm_qkv_k(const bf16* a, const bf16* wt,
                                                  const float* bq, const float* bk, const float* bv,
                                                  bf16* qb, bf16* kb, bf16* vT) {
    gemm_tile<64, 128, EPI_QKV>(a, C_, wt, C_, bq, bk, bv, nullptr, qb, kb, vT, 0, C_,
                                blockIdx.y * 64, blockIdx.x * 128);
}

// split-K over blockIdx.z (4 slices of FF/4, 128x128 tile -> 512 blocks = 2/CU: measured sweet spot)
__global__ __launch_bounds__(256) void gemm_splitk_k(const bf16* A, int lda, const bf16* Bt, int ldb,
                                                     bf16* part, int Ksl) {
    int z = blockIdx.z;
    gemm_tile<128, 128, EPI_PARTIAL>(A + (size_t)z * Ksl, lda, Bt + (size_t)z * Ksl, ldb,
                                     nullptr, nullptr, nullptr, nullptr,
                                     part + (size_t)z * M_ * C_, nullptr, nullptr, C_, Ksl,
                                     blockIdx.y * 128, blockIdx.x * 128);
}

// ---- split-K combine (bf16 partials, +bias +residual into h), optionally fused next-layer LN1 ----
template<int NPART, bool LN>
__global__ __launch_bounds__(256) void combine_ln_k(float* __restrict__ h,
                                                    const bf16* __restrict__ part,
                                                    const float* __restrict__ bias,
                                                    const float* __restrict__ lw,
                                                    const float* __restrict__ lb,
                                                    bf16* __restrict__ aout) {
    int row = blockIdx.x, t = threadIdx.x;
    float4 hv = ((const float4*)(h + (size_t)row * C_))[t];
    float4 bb = ((const float4*)bias)[t];
    hv.x += bb.x; hv.y += bb.y; hv.z += bb.z; hv.w += bb.w;
#pragma unroll
    for (int z = 0; z < NPART; ++z) {
        ushort4 p = ((const ushort4*)((const unsigned short*)part + (size_t)z * M_ * C_ +
                                      (size_t)row * C_))[t];
        hv.x += bf2f(p.x); hv.y += bf2f(p.y); hv.z += bf2f(p.z); hv.w += bf2f(p.w);
    }
    ((float4*)(h + (size_t)row * C_))[t] = hv;

    if constexpr (LN) {
        float s = hv.x + hv.y + hv.z + hv.w;
#pragma unroll
        for (int o = 32; o >= 1; o >>= 1) s += __shfl_xor(s, o);
        __shared__ float red[4];
        int wid = t >> 6, lane = t & 63;
        if (lane == 0) red[wid] = s;
        __syncthreads();
        float mean = (red[0] + red[1] + red[2] + red[3]) * (1.0f / C_);
        __syncthreads();
        float dx = hv.x - mean, dy = hv.y - mean, dz = hv.z - mean, dw = hv.w - mean;
        float ss = dx * dx + dy * dy + dz * dz + dw * dw;
#pragma unroll
        for (int o = 32; o >= 1; o >>= 1) ss += __shfl_xor(ss, o);
        if (lane == 0) red[wid] = ss;
        __syncthreads();
        float var = (red[0] + red[1] + red[2] + red[3]) * (1.0f / C_);
        float rs = rsqrtf(var + 1e-5f);
        float4 wv = ((const float4*)lw)[t];
        float4 bv = ((const float4*)lb)[t];
        bf16* ar = aout + (size_t)row * C_;
        ar[t * 4 + 0] = __float2bfloat16(dx * rs * wv.x + bv.x);
        ar[t * 4 + 1] = __float2bfloat16(dy * rs * wv.y + bv.y);
        ar[t * 4 + 2] = __float2bfloat16(dz * rs * wv.z + bv.z);
        ar[t * 4 + 3] = __float2bfloat16(dw * rs * wv.w + bv.w);
    }
}

// ---------------- Flash attention: one block per (64-q tile, head pair) ----------------
// defer-max (T13). Work-balanced qt remap: co-resident blocks f and f+256 (same x,
// y vs y+16) get qt = x and 15-x, so each CU's pair sums to 17 tile-steps.
__global__ __launch_bounds__(256) void flash_k(const bf16* __restrict__ qb,
                                               const bf16* __restrict__ kb,
                                               const bf16* __restrict__ vT,
                                               bf16* __restrict__ yb) {
    int pair = blockIdx.y;
    int qt = (pair >= 16) ? (15 - blockIdx.x) : blockIdx.x;
    int bb = pair >> 4, hh = pair & 15;
    __shared__ __align__(16) short Ks[2][64 * 64];
    __shared__ __align__(16) short Vs[2][64 * 64];

    int tid = threadIdx.x, wid = tid >> 6, lane = tid & 63, lr = lane & 15, lg = lane >> 4;
    int qrow = qt * 64 + wid * 16 + lr;

    const short* qp = (const short*)qb + ((size_t)(bb * T_ + qrow)) * C_ + hh * 64;
    s16x8 qf[2];
    qf[0] = *(const s16x8*)(qp + lg * 8);
    qf[1] = *(const s16x8*)(qp + 32 + lg * 8);

    const short* kbase = (const short*)kb + ((size_t)bb * T_) * C_ + hh * 64;  // row kv, stride C_
    const short* vbase = (const short*)vT + ((size_t)pair * 64) * T_;          // row d, stride T_

    auto stage = [&](int bf, int t) {
        int kv0 = t * 64;
#pragma unroll
        for (int i = 0; i < 2; ++i) {
            int slot = i * 256 + tid;
            int row = slot >> 3, cs = (slot & 7) ^ (row & 7);
            gload16(kbase + (size_t)(kv0 + row) * C_ + cs * 8, &Ks[bf][(i * 256 + wid * 64) * 8]);
        }
#pragma unroll
        for (int i = 0; i < 2; ++i) {
            int slot = i * 256 + tid;
            int row = slot >> 3, cs = (slot & 7) ^ (row & 7);
            gload16(vbase + (size_t)row * T_ + kv0 + cs * 8, &Vs[bf][(i * 256 + wid * 64) * 8]);
        }
    };

    f32x4 oacc[4];
    const f32x4 z4 = {0.f, 0.f, 0.f, 0.f};
#pragma unroll
    for (int m = 0; m < 4; ++m) oacc[m] = z4;
    float mrun = -INFINITY, lrun = 0.f;

    int srcl[4];
#pragma unroll
    for (int r = 0; r < 4; ++r) srcl[r] = ((((lg << 3) + 2 * r) & 15) >> 2) * 16 + lr;
    bool hihalf = lg >= 2;
    int swz = lr & 7;

    stage(0, 0);
    asm volatile("s_waitcnt vmcnt(0)" ::: "memory");
    __syncthreads();
    int cur = 0;

    for (int t = 0; t <= qt; ++t) {
        int kv0 = t * 64;
        if (t < qt) stage(cur ^ 1, t + 1);  // prefetch next tile into the other buffer

        f32x4 sacc[4];
#pragma unroll
        for (int m = 0; m < 4; ++m) sacc[m] = z4;
#pragma unroll
        for (int ks = 0; ks < 2; ++ks)
#pragma unroll
            for (int mr = 0; mr < 4; ++mr) {
                s16x8 kf = *(const s16x8*)&Ks[cur][(mr * 16 + lr) * 64 + (((ks * 4 + lg) ^ swz) * 8)];
                sacc[mr] = __builtin_amdgcn_mfma_f32_16x16x32_bf16(kf, qf[ks], sacc[mr], 0, 0, 0);
            }

        float p[4][4];
        bool diag = (t == qt);
#pragma unroll
        for (int mr = 0; mr < 4; ++mr)
#pragma unroll
            for (int i = 0; i < 4; ++i) {
                float s = sacc[mr][i] * 0.125f;
                if (diag && (kv0 + mr * 16 + lg * 4 + i) > qrow) s = -1e30f;
                p[mr][i] = s;
            }

        float tmax = p[0][0];
#pragma unroll
        for (int mr = 0; mr < 4; ++mr)
#pragma unroll
            for (int i = 0; i < 4; ++i) tmax = fmaxf(tmax, p[mr][i]);
        tmax = fmaxf(tmax, __shfl_xor(tmax, 16));
        tmax = fmaxf(tmax, __shfl_xor(tmax, 32));

        // defer-max: only rescale when the tile max meaningfully exceeds the running max
        if (!__all(tmax <= mrun + 8.0f)) {
            float mnew = fmaxf(mrun, tmax);
            float corr = __expf(mrun - mnew);
            lrun *= corr;
#pragma unroll
            for (int m = 0; m < 4; ++m)
#pragma unroll
                for (int i = 0; i < 4; ++i) oacc[m][i] *= corr;
            mrun = mnew;
        }

        float tsum = 0.f;
#pragma unroll
        for (int mr = 0; mr < 4; ++mr)
#pragma unroll
            for (int i = 0; i < 4; ++i) {
                p[mr][i] = __expf(p[mr][i] - mrun);
                tsum += p[mr][i];
            }
        tsum += __shfl_xor(tsum, 16);
        tsum += __shfl_xor(tsum, 32);
        lrun += tsum;

        unsigned pk[4][2];
#pragma unroll
        for (int mr = 0; mr < 4; ++mr) {
            pk[mr][0] = packbf(p[mr][0], p[mr][1]);
            pk[mr][1] = packbf(p[mr][2], p[mr][3]);
        }

#pragma unroll
        for (int b2 = 0; b2 < 2; ++b2) {
            union { unsigned u[4]; s16x8 v; } pf;
#pragma unroll
            for (int r = 0; r < 4; ++r) {
                unsigned t0 = (unsigned)__shfl((int)pk[2 * b2][r & 1], srcl[r], 64);
                unsigned t1 = (unsigned)__shfl((int)pk[2 * b2 + 1][r & 1], srcl[r], 64);
                pf.u[r] = hihalf ? t1 : t0;
            }
#pragma unroll
            for (int mr = 0; mr < 4; ++mr) {
                s16x8 av = *(const s16x8*)&Vs[cur][(mr * 16 + lr) * 64 + (((b2 * 4 + lg) ^ swz) * 8)];
                oacc[mr] = __builtin_amdgcn_mfma_f32_16x16x32_bf16(av, pf.v, oacc[mr], 0, 0, 0);
            }
        }

        asm volatile("s_waitcnt vmcnt(0)" ::: "memory");  // drain this iter's prefetch
        __syncthreads();
        cur ^= 1;
    }

    float linv = 1.0f / lrun;
    bf16* yrow = yb + ((size_t)(bb * T_ + qrow)) * C_ + hh * 64;
#pragma unroll
    for (int mr = 0; mr < 4; ++mr) {
        union { unsigned short us[4]; unsigned long long u64; } w;
#pragma unroll
        for (int i = 0; i < 4; ++i)
            w.us[i] = __builtin_bit_cast(unsigned short, __float2bfloat16(oacc[mr][i] * linv));
        *(unsigned long long*)(yrow + mr * 16 + lg * 4) = w.u64;
    }
}

extern "C" void kernel_launch(void* const* d_in, const int* in_sizes, int n_in,
                              void* d_out, int out_size, void* d_ws, size_t ws_size,
                              hipStream_t stream) {
    const float* x     = (const float*)d_in[0];
    const float* Wq    = (const float*)d_in[1];
    const float* Wk    = (const float*)d_in[2];
    const float* Wv    = (const float*)d_in[3];
    const float* Wp    = (const float*)d_in[4];
    const float* bq    = (const float*)d_in[5];
    const float* bk    = (const float*)d_in[6];
    const float* bv    = (const float*)d_in[7];
    const float* bp    = (const float*)d_in[8];
    const float* ln1w  = (const float*)d_in[9];
    const float* ln1b  = (const float*)d_in[10];
    const float* ln2w  = (const float*)d_in[11];
    const float* ln2b  = (const float*)d_in[12];
    const float* W1    = (const float*)d_in[13];
    const float* b1    = (const float*)d_in[14];
    const float* W2    = (const float*)d_in[15];
    const float* b2    = (const float*)d_in[16];
    const float* lnfw  = (const float*)d_in[17];
    const float* lnfb  = (const float*)d_in[18];

    float* h = (float*)d_out;  // residual stream lives in d_out (fp32 [M,C])

    // ---- workspace carve ----
    char* base = (char*)d_ws;
    size_t off = 0;
    auto carve = [&](size_t bytes) {
        char* r = base + off;
        off += (bytes + 255) & ~(size_t)255;
        return r;
    };
    bf16*  a    = (bf16*)carve((size_t)M_ * C_ * 2);
    bf16*  qb   = (bf16*)carve((size_t)M_ * C_ * 2);
    bf16*  kb   = (bf16*)carve((size_t)M_ * C_ * 2);
    bf16*  vT   = (bf16*)carve((size_t)M_ * C_ * 2);      // [B*H*64, T]
    bf16*  yb   = (bf16*)carve((size_t)M_ * C_ * 2);
    bf16*  hid  = (bf16*)carve((size_t)M_ * FF * 2);
    bf16*  part = (bf16*)carve((size_t)4 * M_ * C_ * 2);  // split-K partials, bf16 (16MB)
    bf16*  wt   = (bf16*)carve((size_t)WSLAB * 2);        // per-layer transposed weights (24MB)

    dim3 tb(256);

    // LN1 for layer 0 reads x directly (later layers fused into combine_ln_k)
    ln_kernel<bf16><<<M_, tb, 0, stream>>>(x, ln1w, ln1b, a);

    for (int l = 0; l < L_; ++l) {
        // per-layer weight transpose (keeps slab cache-hot for its consumers)
        transpose_all_k<<<dim3(3072, 1, 1), tb, 0, stream>>>(Wq, Wk, Wv, Wp, W1, W2, wt, l);

        // QKV fused GEMM (64x128 tile: 768 blocks = 3/CU)
        gemm_qkv_k<<<dim3(24, 32), tb, 0, stream>>>(a, wt, bq + l * C_, bk + l * C_, bv + l * C_,
                                                    qb, kb, vT);

        // flash attention (work-balanced qt remap)
        flash_k<<<dim3(16, 32), tb, 0, stream>>>(qb, kb, vT, yb);

        // out proj + residual (64x64 tile: 512 blocks = 2/CU)
        gemm_k<64, 64, EPI_RESID><<<dim3(16, 32), tb, 0, stream>>>(
            yb, C_, wt + (size_t)3 * 1048576, C_, bp + l * C_, (l == 0) ? x : h, h, C_, C_);

        // LN2 -> a
        ln_kernel<bf16><<<M_, tb, 0, stream>>>(h, ln2w + l * C_, ln2b + l * C_, a);

        // MLP up + GELU -> hid (128x128 tile: 512 blocks = 2/CU, measured sweet spot)
        gemm_k<128, 128, EPI_GELU><<<dim3(FF / 128, M_ / 128), tb, 0, stream>>>(
            a, C_, wt + (size_t)4 * 1048576, C_, b1 + l * FF, nullptr, hid, FF, C_);

        // MLP down: split-K=4 bf16 partials (128x128, 512 blocks = 2/CU), then combine
        gemm_splitk_k<<<dim3(8, 16, 4), tb, 0, stream>>>(hid, FF, wt + (size_t)8 * 1048576, FF,
                                                         part, FF / 4);
        if (l < L_ - 1)
            combine_ln_k<4, true><<<M_, tb, 0, stream>>>(h, part, b2 + l * C_,
                                                         ln1w + (l + 1) * C_, ln1b + (l + 1) * C_, a);
        else
            combine_ln_k<4, false><<<M_, tb, 0, stream>>>(h, part, b2 + l * C_,
                                                          nullptr, nullptr, nullptr);
    }

    // final LN in place (fp32 out)
    ln_kernel<float><<<M_, tb, 0, stream>>>(h, lnfw, lnfb, h);
}